// Round 7
// baseline (33.145 us; speedup 1.0000x reference)
//
#include <hip/hip_runtime.h>
#include <math.h>

// ChamferLoss via matrix cores — v_mfma_f32_32x32x16_f16, K=16 embedding:
//   A-side a: (ax,ay,az, 1, -|a|^2/2, 0...)   (k=0..7 on lanes 0..31)
//   B-side b: (bx,by,bz, -|b|^2/2, 1, 0...)
// C[i][j] = a.b - (|a|^2+|b|^2)/2 = -dist^2/2 ; min dist^2 = -2 max C.
// k=8..15 (lanes 32..63) are all zero -> those lanes read a shared 16B
// zero slot (LDS broadcast), so the A-table is only 32KB.
// Distance-2 register prefetch of A-fragments hides ds_read latency.

typedef _Float16 half8 __attribute__((ext_vector_type(8)));
typedef float floatx16 __attribute__((ext_vector_type(16)));

constexpr int B_ = 64;
constexpr int N_ = 2048;
constexpr int NT = N_ / 32;        // 64 row-tiles
constexpr int BLOCK = 256;         // 4 waves
constexpr int WPB = 4;
constexpr int BFRAGS = 2;          // col-tiles per wave
constexpr int IBLK = NT / (WPB * BFRAGS);   // 8 blocks along col-tile axis

__global__ __launch_bounds__(BLOCK, 4) void chamfer_mfma_kernel(
    const float* __restrict__ p, const float* __restrict__ q,
    float* __restrict__ out)
{
    __shared__ half8 Aarr[NT * 32 + 1];    // 32KB + zero slot at [NT*32]
    __shared__ float wsum[WPB];

    const int dir = blockIdx.z;            // 0: A=q,B=p ; 1: A=p,B=q
    const int b   = blockIdx.y;
    const float4* rowsA = (const float4*)((dir == 0 ? q : p) + (size_t)b * N_ * 4);
    const float4* colsB = (const float4*)((dir == 0 ? p : q) + (size_t)b * N_ * 4);

    // Build A-fragments (lanes 0..31 data only) for the whole batch.
    // A frag layout (32x32x16f16): lane l (<32) holds A[row=l][k=e].
    for (int j = threadIdx.x; j < N_; j += BLOCK) {
        float4 v = rowsA[j];
        _Float16 x = (_Float16)v.y, y = (_Float16)v.z, z = (_Float16)v.w;
        float xf = (float)x, yf = (float)y, zf = (float)z;
        float sq = fmaf(xf, xf, fmaf(yf, yf, zf * zf));
        half8 lo;
        lo[0] = x; lo[1] = y; lo[2] = z; lo[3] = (_Float16)1.0f;
        lo[4] = (_Float16)(-0.5f * sq);
        lo[5] = (_Float16)0.0f; lo[6] = (_Float16)0.0f; lo[7] = (_Float16)0.0f;
        Aarr[(j >> 5) * 32 + (j & 31)] = lo;
    }
    if (threadIdx.x == 0) {
        half8 z8;
#pragma unroll
        for (int e = 0; e < 8; ++e) z8[e] = (_Float16)0.0f;
        Aarr[NT * 32] = z8;
    }

    // Two B-role fragments per wave (col-tiles 2W, 2W+1).
    const int lane = threadIdx.x & 63;
    const int wid  = threadIdx.x >> 6;
    const int W    = blockIdx.x * WPB + wid;
    half8 bf[BFRAGS];
#pragma unroll
    for (int t = 0; t < BFRAGS; ++t) {
        float4 v = colsB[(W * BFRAGS + t) * 32 + (lane & 31)];
        _Float16 x = (_Float16)v.y, y = (_Float16)v.z, z = (_Float16)v.w;
        float xf = (float)x, yf = (float)y, zf = (float)z;
        float sq = fmaf(xf, xf, fmaf(yf, yf, zf * zf));
#pragma unroll
        for (int e = 0; e < 8; ++e) bf[t][e] = (_Float16)0.0f;
        if (lane < 32) {
            bf[t][0] = x; bf[t][1] = y; bf[t][2] = z;
            bf[t][3] = (_Float16)(-0.5f * sq);
            bf[t][4] = (_Float16)1.0f;
        }
    }
    __syncthreads();

    // Per-lane A pointer: lanes 32..63 pin to the zero slot (step 0).
    const half8* aptr = (lane < 32) ? &Aarr[lane] : &Aarr[NT * 32];
    const int astep = (lane < 32) ? 32 : 0;

    floatx16 zero;
#pragma unroll
    for (int i = 0; i < 16; ++i) zero[i] = 0.0f;

    // Distance-2 register prefetch pipeline over the 64 row-tiles.
    half8 a0 = aptr[0];
    half8 a1 = aptr[astep];
    aptr += 2 * astep;

    float cmx0 = -3.4e38f, cmx1 = -3.4e38f;
#pragma unroll 2
    for (int J = 0; J < NT; ++J) {
        half8 an = (J < NT - 2) ? aptr[0] : a1;   // prefetch J+2
        aptr += astep;
        floatx16 C0 = __builtin_amdgcn_mfma_f32_32x32x16_f16(a0, bf[0], zero, 0, 0, 0);
        floatx16 C1 = __builtin_amdgcn_mfma_f32_32x32x16_f16(a0, bf[1], zero, 0, 0, 0);
        a0 = a1; a1 = an;
        {
            float m0 = fmaxf(fmaxf(C0[0],  C0[1]),  C0[2]);
            float m1 = fmaxf(fmaxf(C0[3],  C0[4]),  C0[5]);
            float m2 = fmaxf(fmaxf(C0[6],  C0[7]),  C0[8]);
            float m3 = fmaxf(fmaxf(C0[9],  C0[10]), C0[11]);
            float m4 = fmaxf(fmaxf(C0[12], C0[13]), C0[14]);
            float m5 = fmaxf(fmaxf(m0, m1), C0[15]);
            float m6 = fmaxf(fmaxf(m2, m3), m4);
            cmx0 = fmaxf(cmx0, fmaxf(m5, m6));
        }
        {
            float m0 = fmaxf(fmaxf(C1[0],  C1[1]),  C1[2]);
            float m1 = fmaxf(fmaxf(C1[3],  C1[4]),  C1[5]);
            float m2 = fmaxf(fmaxf(C1[6],  C1[7]),  C1[8]);
            float m3 = fmaxf(fmaxf(C1[9],  C1[10]), C1[11]);
            float m4 = fmaxf(fmaxf(C1[12], C1[13]), C1[14]);
            float m5 = fmaxf(fmaxf(m0, m1), C1[15]);
            float m6 = fmaxf(fmaxf(m2, m3), m4);
            cmx1 = fmaxf(cmx1, fmaxf(m5, m6));
        }
    }

    // Combine the two lane-halves; each column then held by 2 lanes.
    cmx0 = fmaxf(cmx0, __shfl_xor(cmx0, 32, 64));
    cmx1 = fmaxf(cmx1, __shfl_xor(cmx1, 32, 64));

    float local = sqrtf(fmaxf(-2.0f * cmx0, 0.0f) + 1e-16f)
                + sqrtf(fmaxf(-2.0f * cmx1, 0.0f) + 1e-16f);

#pragma unroll
    for (int off = 32; off > 0; off >>= 1)
        local += __shfl_xor(local, off, 64);

    if (lane == 0) wsum[wid] = local;
    __syncthreads();
    if (threadIdx.x == 0) {
        float s = 0.0f;
#pragma unroll
        for (int w = 0; w < WPB; ++w) s += wsum[w];
        atomicAdd(out, 0.25f * s);   // 0.5 chamfer factor * 0.5 lane-dup
    }
}

extern "C" void kernel_launch(void* const* d_in, const int* in_sizes, int n_in,
                              void* d_out, int out_size, void* d_ws, size_t ws_size,
                              hipStream_t stream) {
    const float* p = (const float*)d_in[0];
    const float* q = (const float*)d_in[1];
    float* out = (float*)d_out;

    hipMemsetAsync(out, 0, sizeof(float), stream);

    dim3 grid(IBLK, B_, 2);                 // 8 x 64 x 2 = 1024 blocks
    chamfer_mfma_kernel<<<grid, BLOCK, 0, stream>>>(p, q, out);
}

// Round 8
// 23.561 us; speedup vs baseline: 1.4068x; 1.4068x over previous
//
#include <hip/hip_runtime.h>
#include <math.h>

// ChamferLoss via matrix cores — v_mfma_f32_32x32x16_f16 (K=16).
// Embedding:  A-side a: (ax,ay,az, 1, -|a|^2/2, 0..0)
//             B-side b: (bx,by,bz, -|b|^2/2, 1, 0..0)
// C[i][j] = a.b - (|a|^2+|b|^2)/2 = -dist^2/2 ; min dist^2 = -2 max C.
// Kernel 1: per-block partial sums -> plain store to d_ws (no memset needed).
// Kernel 2: single block reduces the 512 partials -> d_out.

typedef _Float16 half8 __attribute__((ext_vector_type(8)));
typedef float floatx16 __attribute__((ext_vector_type(16)));

constexpr int B_ = 64;
constexpr int N_ = 2048;
constexpr int NT = N_ / 32;        // 64 tiles per side
constexpr int BLOCK = 512;         // 8 waves
constexpr int WPB = 8;
constexpr int BFRAGS = 2;          // col-tiles per wave
constexpr int IBLK = NT / (WPB * BFRAGS);   // 4 blocks along col-tile axis
constexpr int NBLK = IBLK * B_ * 2;         // 512 partials

__global__ __launch_bounds__(BLOCK, 4) void chamfer_mfma_kernel(
    const float* __restrict__ p, const float* __restrict__ q,
    float* __restrict__ partials)
{
    __shared__ half8 Aarr[NT * 64];       // 64 KB: per-tile A fragments
    __shared__ float wsum[WPB];

    const int dir = blockIdx.z;            // 0: A=q,B=p ; 1: A=p,B=q
    const int b   = blockIdx.y;
    const float4* rowsA = (const float4*)((dir == 0 ? q : p) + (size_t)b * N_ * 4);
    const float4* colsB = (const float4*)((dir == 0 ? p : q) + (size_t)b * N_ * 4);

    // Build all A-role fragments for this batch in LDS.
    // A frag layout (32x32x16f16): lane l holds A[row=l%32][k=8*(l/32)+e].
    for (int j = threadIdx.x; j < N_; j += BLOCK) {
        float4 v = rowsA[j];
        _Float16 x = (_Float16)v.y, y = (_Float16)v.z, z = (_Float16)v.w;
        float xf = (float)x, yf = (float)y, zf = (float)z;
        float sq = fmaf(xf, xf, fmaf(yf, yf, zf * zf));
        half8 lo;
        lo[0] = x; lo[1] = y; lo[2] = z; lo[3] = (_Float16)1.0f;
        lo[4] = (_Float16)(-0.5f * sq);
        lo[5] = (_Float16)0.0f; lo[6] = (_Float16)0.0f; lo[7] = (_Float16)0.0f;
        half8 zero8;
#pragma unroll
        for (int e = 0; e < 8; ++e) zero8[e] = (_Float16)0.0f;
        const int tile = j >> 5, r = j & 31;
        Aarr[tile * 64 + r]      = lo;     // lanes 0..31: k=0..7
        Aarr[tile * 64 + 32 + r] = zero8;  // lanes 32..63: k=8..15 (zero)
    }

    // Two B-role fragments per wave (col-tiles 2W, 2W+1).
    // B frag layout: lane l holds B[k=8*(l/32)+e][col=l%32].
    const int lane = threadIdx.x & 63;
    const int wid  = threadIdx.x >> 6;
    const int W    = blockIdx.x * WPB + wid;
    half8 bf[BFRAGS];
#pragma unroll
    for (int t = 0; t < BFRAGS; ++t) {
        float4 v = colsB[(W * BFRAGS + t) * 32 + (lane & 31)];
        _Float16 x = (_Float16)v.y, y = (_Float16)v.z, z = (_Float16)v.w;
        float xf = (float)x, yf = (float)y, zf = (float)z;
        float sq = fmaf(xf, xf, fmaf(yf, yf, zf * zf));
#pragma unroll
        for (int e = 0; e < 8; ++e) bf[t][e] = (_Float16)0.0f;
        if (lane < 32) {
            bf[t][0] = x; bf[t][1] = y; bf[t][2] = z;
            bf[t][3] = (_Float16)(-0.5f * sq);
            bf[t][4] = (_Float16)1.0f;
        }
    }
    __syncthreads();

    floatx16 zero;
#pragma unroll
    for (int i = 0; i < 16; ++i) zero[i] = 0.0f;

    // Sweep all row-tiles; one A-frag ds_read_b128 feeds BFRAGS MFMAs.
    float cmx0 = -3.4e38f, cmx1 = -3.4e38f;
#pragma unroll 4
    for (int J = 0; J < NT; ++J) {
        half8 afrag = Aarr[J * 64 + lane];
        floatx16 C0 = __builtin_amdgcn_mfma_f32_32x32x16_f16(afrag, bf[0], zero, 0, 0, 0);
        floatx16 C1 = __builtin_amdgcn_mfma_f32_32x32x16_f16(afrag, bf[1], zero, 0, 0, 0);
        {
            float m0 = fmaxf(fmaxf(C0[0],  C0[1]),  C0[2]);
            float m1 = fmaxf(fmaxf(C0[3],  C0[4]),  C0[5]);
            float m2 = fmaxf(fmaxf(C0[6],  C0[7]),  C0[8]);
            float m3 = fmaxf(fmaxf(C0[9],  C0[10]), C0[11]);
            float m4 = fmaxf(fmaxf(C0[12], C0[13]), C0[14]);
            float m5 = fmaxf(fmaxf(m0, m1), C0[15]);
            float m6 = fmaxf(fmaxf(m2, m3), m4);
            cmx0 = fmaxf(cmx0, fmaxf(m5, m6));
        }
        {
            float m0 = fmaxf(fmaxf(C1[0],  C1[1]),  C1[2]);
            float m1 = fmaxf(fmaxf(C1[3],  C1[4]),  C1[5]);
            float m2 = fmaxf(fmaxf(C1[6],  C1[7]),  C1[8]);
            float m3 = fmaxf(fmaxf(C1[9],  C1[10]), C1[11]);
            float m4 = fmaxf(fmaxf(C1[12], C1[13]), C1[14]);
            float m5 = fmaxf(fmaxf(m0, m1), C1[15]);
            float m6 = fmaxf(fmaxf(m2, m3), m4);
            cmx1 = fmaxf(cmx1, fmaxf(m5, m6));
        }
    }

    // Combine the two lane-halves; each column then held by 2 lanes.
    cmx0 = fmaxf(cmx0, __shfl_xor(cmx0, 32, 64));
    cmx1 = fmaxf(cmx1, __shfl_xor(cmx1, 32, 64));

    float local = sqrtf(fmaxf(-2.0f * cmx0, 0.0f) + 1e-16f)
                + sqrtf(fmaxf(-2.0f * cmx1, 0.0f) + 1e-16f);

#pragma unroll
    for (int off = 32; off > 0; off >>= 1)
        local += __shfl_xor(local, off, 64);

    if (lane == 0) wsum[wid] = local;
    __syncthreads();
    if (threadIdx.x == 0) {
        float s = 0.0f;
#pragma unroll
        for (int w = 0; w < WPB; ++w) s += wsum[w];
        // 0.5 chamfer factor * 0.5 lane-dup; plain store, no init needed.
        partials[(blockIdx.z * B_ + blockIdx.y) * IBLK + blockIdx.x] = 0.25f * s;
    }
}

__global__ __launch_bounds__(NBLK) void chamfer_reduce_kernel(
    const float* __restrict__ partials, float* __restrict__ out)
{
    float v = partials[threadIdx.x];
#pragma unroll
    for (int off = 32; off > 0; off >>= 1)
        v += __shfl_xor(v, off, 64);

    __shared__ float wsum[NBLK / 64];
    if ((threadIdx.x & 63) == 0) wsum[threadIdx.x >> 6] = v;
    __syncthreads();
    if (threadIdx.x == 0) {
        float s = 0.0f;
#pragma unroll
        for (int w = 0; w < NBLK / 64; ++w) s += wsum[w];
        out[0] = s;
    }
}

extern "C" void kernel_launch(void* const* d_in, const int* in_sizes, int n_in,
                              void* d_out, int out_size, void* d_ws, size_t ws_size,
                              hipStream_t stream) {
    const float* p = (const float*)d_in[0];
    const float* q = (const float*)d_in[1];
    float* out = (float*)d_out;
    float* partials = (float*)d_ws;

    dim3 grid(IBLK, B_, 2);                 // 4 x 64 x 2 = 512 blocks
    chamfer_mfma_kernel<<<grid, BLOCK, 0, stream>>>(p, q, partials);
    chamfer_reduce_kernel<<<1, NBLK, 0, stream>>>(partials, out);
}